// Round 13
// baseline (462.064 us; speedup 1.0000x reference)
//
#include <hip/hip_runtime.h>
#include <hip/hip_bf16.h>

typedef unsigned short u16;
typedef __attribute__((ext_vector_type(8))) short short8;
typedef __attribute__((ext_vector_type(4))) float f32x4;
typedef __attribute__((ext_vector_type(16))) float f32x16;
typedef __attribute__((ext_vector_type(2))) unsigned uint2v;

#define ATT_B 4
#define ATT_N 4096
#define ATT_M 1024
#define ATT_H 16
#define CBLK 64
#define NT (ATT_M / CBLK)

__device__ inline u16 f2bf(float f) {
  union { float f; unsigned u; } x; x.f = f;
  unsigned r = x.u + 0x7fffu + ((x.u >> 16) & 1u);
  return (u16)(r >> 16);
}

// packed f32x2 -> bf16x2 (RNE), low word = lo
__device__ inline unsigned pk_bf16(float lo, float hi) {
  unsigned r;
  asm("v_cvt_pk_bf16_f32 %0, %1, %2" : "=v"(r) : "v"(lo), "v"(hi));
  return r;
}

// raw v_exp_f32 (2^x), no libm range fixup — inputs here are bounded |x|<~40
__device__ inline float exp2_raw(float x) {
  float r;
  asm("v_exp_f32 %0, %1" : "=v"(r) : "v"(x));
  return r;
}

__device__ inline void gload_lds16(const u16* g, u16* l) {
  __builtin_amdgcn_global_load_lds(
      (const __attribute__((address_space(1))) void*)g,
      (__attribute__((address_space(3))) void*)l, 16, 0, 0);
}

// ------- prep: weight transpose-casts + x/ctx casts in ONE launch ----------
__global__ __launch_bounds__(256) void prep_kernel(
    const float* __restrict__ x, u16* __restrict__ xb, int n4x,
    const float* __restrict__ ctx, u16* __restrict__ cb, int n4c,
    const float* __restrict__ Wq, const float* __restrict__ Wk,
    const float* __restrict__ Wv, const float* __restrict__ Wo,
    u16* __restrict__ wqt, u16* __restrict__ wkt,
    u16* __restrict__ wvt, u16* __restrict__ wot) {
  const int blk = blockIdx.x;
  const int tid = threadIdx.x;
  if (blk < 4096) {
    const int z = blk >> 10;
    const float* W = (z == 0) ? Wq : (z == 1) ? Wk : (z == 2) ? Wv : Wo;
    u16* Wt = (z == 0) ? wqt : (z == 1) ? wkt : (z == 2) ? wvt : wot;
    const int K = (z == 0 || z == 3) ? 1024 : 768;
    const int k0 = ((blk >> 5) & 31) * 32;
    if (k0 >= K) return;
    const int n0 = (blk & 31) * 32;
    __shared__ float T[32][33];
    const int tx = tid & 31, ty = tid >> 5;   // (32, 8)
#pragma unroll
    for (int i = 0; i < 4; ++i)
      T[ty + i * 8][tx] = W[(size_t)(k0 + ty + i * 8) * 1024 + n0 + tx];
    __syncthreads();
#pragma unroll
    for (int i = 0; i < 4; ++i)
      Wt[(size_t)(n0 + ty + i * 8) * K + k0 + tx] = f2bf(T[tx][ty + i * 8]);
  } else {
    int i = (blk - 4096) * 256 + tid;
    const float* src;
    u16* dst;
    if (i < n4x) {
      src = x; dst = xb;
    } else {
      i -= n4x;
      if (i >= n4c) return;
      src = ctx; dst = cb;
    }
    const float4 v = reinterpret_cast<const float4*>(src)[i];
    uint2 o;
    o.x = pk_bf16(v.x, v.y);
    o.y = pk_bf16(v.z, v.w);
    reinterpret_cast<uint2*>(dst)[i] = o;
  }
}

// -------- gemm body: BK=64, row-major LDS + XOR swizzle, XCD swizzle -------
template <int F32OUT>
__device__ __forceinline__ void gemm_body(const u16* __restrict__ A,
                                          const u16* __restrict__ Bt,
                                          u16* __restrict__ Cb,
                                          float* __restrict__ Cf,
                                          const float* __restrict__ bias,
                                          float scale, int N, int K,
                                          unsigned orig, unsigned gx, unsigned nwg,
                                          u16* As, u16* Bs) {
  const int tid = threadIdx.x;
  const int lane = tid & 63;
  const int w = tid >> 6;
  const int lr = lane & 15;
  const int lk = lane >> 4;
  const int wm = w >> 1, wn = w & 1;

  // XCD-aware swizzle (segment sizes always % 8 == 0)
  const unsigned cpx = nwg >> 3;
  const unsigned swz = (orig & 7u) * cpx + (orig >> 3);
  const int brow = (int)(swz / gx) * 128;
  const int bcol = (int)(swz % gx) * 128;

  const int gr = lane >> 3;              // row within 8-row group
  const int gc = (lane & 7) ^ gr;        // permuted 16B chunk (0..7)

  f32x4 acc[4][4];
#pragma unroll
  for (int mi = 0; mi < 4; ++mi)
#pragma unroll
    for (int ni = 0; ni < 4; ++ni) acc[mi][ni] = f32x4{0.f, 0.f, 0.f, 0.f};

  for (int k0 = 0; k0 < K; k0 += 64) {
#pragma unroll
    for (int i = 0; i < 4; ++i) {
      const int g = w * 4 + i;           // 8-row group 0..15, wave-uniform
      gload_lds16(A + (size_t)(brow + g * 8 + gr) * K + k0 + gc * 8, &As[g * 512]);
      gload_lds16(Bt + (size_t)(bcol + g * 8 + gr) * K + k0 + gc * 8, &Bs[g * 512]);
    }
    __syncthreads();
    short8 a[4][2], bb[4][2];
#pragma unroll
    for (int mi = 0; mi < 4; ++mi) {
      const int row = wm * 64 + mi * 16 + lr;
#pragma unroll
      for (int kk = 0; kk < 2; ++kk)
        a[mi][kk] = *reinterpret_cast<const short8*>(
            &As[row * 64 + (((kk * 4 + lk) ^ (lr & 7)) * 8)]);
    }
#pragma unroll
    for (int ni = 0; ni < 4; ++ni) {
      const int row = wn * 64 + ni * 16 + lr;
#pragma unroll
      for (int kk = 0; kk < 2; ++kk)
        bb[ni][kk] = *reinterpret_cast<const short8*>(
            &Bs[row * 64 + (((kk * 4 + lk) ^ (lr & 7)) * 8)]);
    }
#pragma unroll
    for (int mi = 0; mi < 4; ++mi)
#pragma unroll
      for (int ni = 0; ni < 4; ++ni)
#pragma unroll
        for (int kk = 0; kk < 2; ++kk)
          acc[mi][ni] = __builtin_amdgcn_mfma_f32_16x16x32_bf16(
              a[mi][kk], bb[ni][kk], acc[mi][ni], 0, 0, 0);
    __syncthreads();
  }

#pragma unroll
  for (int mi = 0; mi < 4; ++mi)
#pragma unroll
    for (int ni = 0; ni < 4; ++ni)
#pragma unroll
      for (int r = 0; r < 4; ++r) {
        const size_t row = (size_t)(brow + wm * 64 + mi * 16 + lk * 4 + r);
        const int col = bcol + wn * 64 + ni * 16 + lr;
        if (F32OUT)
          Cf[row * N + col] = acc[mi][ni][r] + bias[col];
        else
          Cb[row * N + col] = f2bf(acc[mi][ni][r] * scale);
      }
}

// ---- proj3: Q-proj ∥ K-proj ∥ V^T-proj in one dispatch (segment decode) ---
__global__ __launch_bounds__(256) void proj3(
    const u16* __restrict__ xb, const u16* __restrict__ wqt, u16* __restrict__ Qb,
    float qscale,
    const u16* __restrict__ cb, const u16* __restrict__ wkt, u16* __restrict__ Kb,
    const u16* __restrict__ wvt, u16* __restrict__ VTb) {
  __shared__ u16 As[128 * 64];
  __shared__ u16 Bs[128 * 64];
  const unsigned blk = blockIdx.x;
  if (blk < 1024)
    gemm_body<0>(xb, wqt, Qb, nullptr, nullptr, qscale, 1024, 1024,
                 blk, 8u, 1024u, As, Bs);
  else if (blk < 1280)
    gemm_body<0>(cb, wkt, Kb, nullptr, nullptr, 1.0f, 1024, 768,
                 blk - 1024u, 8u, 256u, As, Bs);
  else
    gemm_body<0>(wvt, cb, VTb, nullptr, nullptr, 1.0f, 4096, 768,
                 blk - 1280u, 32u, 256u, As, Bs);
}

// ---- out-projection (f32 out + bias) --------------------------------------
template <int F32OUT>
__global__ __launch_bounds__(256) void gemm_bt(const u16* __restrict__ A,
                                               const u16* __restrict__ Bt,
                                               u16* __restrict__ Cb,
                                               float* __restrict__ Cf,
                                               const float* __restrict__ bias,
                                               float scale, int N, int K) {
  __shared__ u16 As[128 * 64];
  __shared__ u16 Bs[128 * 64];
  const unsigned gx = gridDim.x;
  const unsigned nwg = gx * gridDim.y;
  const unsigned orig = blockIdx.y * gx + blockIdx.x;
  gemm_body<F32OUT>(A, Bt, Cb, Cf, bias, scale, N, K, orig, gx, nwg, As, Bs);
}

// ---------------- flash attention v8: 64 q-rows per wave -------------------
// grid: (N/256, B*H), 256 threads = 4 waves x 64 q-rows. CBLK=64.
// Each wave holds TWO Q-fragments (f=0,1); QK^T runs f sequentially (st
// reused, K-frags re-read) -> 24 ds_read serve 32 MFMA per tile (vs 16/20
// at 32q). Row-sum is scalar per-lane (q = lane&31 is lane-local in the
// swapped layout) -> no ones-MFMA (-20% matrix-pipe work), epilogue
// redistributes via 1KB lsw. PV V-frags shared by both f.
// No max subtraction (scores bounded; shift cancels in the divide).
__global__ __launch_bounds__(256, 3) void attn_kernel(const u16* __restrict__ Qg,
                                                      const u16* __restrict__ Kg,
                                                      const u16* __restrict__ VTg,
                                                      u16* __restrict__ AO) {
  __shared__ u16 Ks[2][8][512];   // K frag f=ci*4+kc: K[ct+ci*32+l][kc*16+hi*8+j]
  __shared__ u16 Vs[2][8][512];   // V frag f=dj*4+kc: V[ct+kc*16+hi*8+j][dj*32+l]
  __shared__ float lsw[4][2][32];

  const int tid = threadIdx.x;
  const int lane = tid & 63;
  const int w = tid >> 6;          // 0..3
  const int l = lane & 31;
  const int hi = lane >> 5;
  const int qt = blockIdx.x;
  const int bh = blockIdx.y;
  const int b = bh >> 4, h = bh & 15;
  const int qbase = qt * 256 + w * 64;

  short8 qf[2][4];
#pragma unroll
  for (int f = 0; f < 2; ++f)
#pragma unroll
    for (int kc = 0; kc < 4; ++kc)
      qf[f][kc] = *reinterpret_cast<const short8*>(
          Qg + (size_t)(b * ATT_N + qbase + f * 32 + l) * 1024 + h * 64 + kc * 16 + hi * 8);

  // wave w stages K frags {2w,2w+1}, V frags {2w,2w+1}
  const int fa = 2 * w, fb = 2 * w + 1;
  const u16* ksrcA = Kg + (size_t)(b * ATT_M + (fa >> 2) * 32 + l) * 1024 + h * 64 + (fa & 3) * 16 + hi * 8;
  const u16* ksrcB = Kg + (size_t)(b * ATT_M + (fb >> 2) * 32 + l) * 1024 + h * 64 + (fb & 3) * 16 + hi * 8;
  const u16* vsrcA = VTg + (size_t)(h * 64 + (fa >> 2) * 32 + l) * (ATT_B * ATT_M) + b * ATT_M + (fa & 3) * 16 + hi * 8;
  const u16* vsrcB = VTg + (size_t)(h * 64 + (fb >> 2) * 32 + l) * (ATT_B * ATT_M) + b * ATT_M + (fb & 3) * 16 + hi * 8;

  f32x16 Oacc[2][2];
  float lsum[2] = {0.f, 0.f};
#pragma unroll
  for (int f = 0; f < 2; ++f)
#pragma unroll
    for (int r = 0; r < 16; ++r) { Oacc[f][0][r] = 0.f; Oacc[f][1][r] = 0.f; }

  gload_lds16(ksrcA, &Ks[0][fa][0]);
  gload_lds16(ksrcB, &Ks[0][fb][0]);
  gload_lds16(vsrcA, &Vs[0][fa][0]);
  gload_lds16(vsrcB, &Vs[0][fb][0]);
  __syncthreads();

  int buf = 0;
  for (int t = 0; t < NT; ++t) {
    if (t + 1 < NT) {
      const size_t kadv = (size_t)(t + 1) * CBLK * 1024;
      const size_t vadv = (size_t)(t + 1) * CBLK;
      gload_lds16(ksrcA + kadv, &Ks[buf ^ 1][fa][0]);
      gload_lds16(ksrcB + kadv, &Ks[buf ^ 1][fb][0]);
      gload_lds16(vsrcA + vadv, &Vs[buf ^ 1][fa][0]);
      gload_lds16(vsrcB + vadv, &Vs[buf ^ 1][fb][0]);
    }

    short8 pa[2][4];
#pragma unroll
    for (int f = 0; f < 2; ++f) {
      // ---- S^T = K Q^T for this q-fragment ----
      f32x16 st[2];
#pragma unroll
      for (int r = 0; r < 16; ++r) { st[0][r] = 0.f; st[1][r] = 0.f; }
      __builtin_amdgcn_s_setprio(1);
#pragma unroll
      for (int ci = 0; ci < 2; ++ci)
#pragma unroll
        for (int kc = 0; kc < 4; ++kc) {
          short8 kb = *reinterpret_cast<const short8*>(&Ks[buf][ci * 4 + kc][lane * 8]);
          st[ci] = __builtin_amdgcn_mfma_f32_32x32x16_bf16(kb, qf[f][kc], st[ci], 0, 0, 0);
        }
      __builtin_amdgcn_s_setprio(0);

      // ---- P = exp2; scalar lane-local row sum; pack to PV A-frags ----
#pragma unroll
      for (int ci = 0; ci < 2; ++ci) {
        float p[16];
        float s = 0.f;
#pragma unroll
        for (int r = 0; r < 16; ++r) { p[r] = exp2_raw(st[ci][r]); s += p[r]; }
        lsum[f] += s;
        unsigned Y0 = pk_bf16(p[0], p[1]),   Y1 = pk_bf16(p[2], p[3]);
        unsigned Y2 = pk_bf16(p[4], p[5]),   Y3 = pk_bf16(p[6], p[7]);
        unsigned Y4 = pk_bf16(p[8], p[9]),   Y5 = pk_bf16(p[10], p[11]);
        unsigned Y6 = pk_bf16(p[12], p[13]), Y7 = pk_bf16(p[14], p[15]);
        uint2v s02 = __builtin_amdgcn_permlane32_swap(Y0, Y2, false, false);
        uint2v s13 = __builtin_amdgcn_permlane32_swap(Y1, Y3, false, false);
        uint2v s46 = __builtin_amdgcn_permlane32_swap(Y4, Y6, false, false);
        uint2v s57 = __builtin_amdgcn_permlane32_swap(Y5, Y7, false, false);
        union { unsigned u[4]; short8 s; } f0, f1;
        f0.u[0] = s02.x; f0.u[1] = s13.x; f0.u[2] = s02.y; f0.u[3] = s13.y;
        f1.u[0] = s46.x; f1.u[1] = s57.x; f1.u[2] = s46.y; f1.u[3] = s57.y;
        pa[f][ci * 2 + 0] = f0.s;
        pa[f][ci * 2 + 1] = f1.s;
      }
    }

    // ---- O += P V (V-frags shared by both q-fragments) ----
    __builtin_amdgcn_s_setprio(1);
#pragma unroll
    for (int kcc = 0; kcc < 4; ++kcc)
#pragma unroll
      for (int dj = 0; dj < 2; ++dj) {
        short8 vb = *reinterpret_cast<const short8*>(&Vs[buf][dj * 4 + kcc][lane * 8]);
        Oacc[0][dj] = __builtin_amdgcn_mfma_f32_32x32x16_bf16(pa[0][kcc], vb, Oacc[0][dj], 0, 0, 0);
        Oacc[1][dj] = __builtin_amdgcn_mfma_f32_32x32x16_bf16(pa[1][kcc], vb, Oacc[1][dj], 0, 0, 0);
      }
    __builtin_amdgcn_s_setprio(0);

    __syncthreads();
    buf ^= 1;
  }

  // ---- epilogue: reduce + redistribute row sums, divide, write ----
#pragma unroll
  for (int f = 0; f < 2; ++f) lsum[f] += __shfl_xor(lsum[f], 32);
  if (hi == 0) { lsw[w][0][l] = lsum[0]; lsw[w][1][l] = lsum[1]; }
  __syncthreads();
#pragma unroll
  for (int f = 0; f < 2; ++f)
#pragma unroll
    for (int r = 0; r < 16; ++r) {
      const int crow = (r & 3) + 8 * (r >> 2) + 4 * hi;
      const float inv = __builtin_amdgcn_rcpf(lsw[w][f][crow]);
      const size_t row = (size_t)(b * ATT_N + qbase + f * 32 + crow);
#pragma unroll
      for (int dj = 0; dj < 2; ++dj)
        AO[row * 1024 + h * 64 + dj * 32 + l] = f2bf(Oacc[f][dj][r] * inv);
    }
}

// ---------------------------------------------------------------------------
extern "C" void kernel_launch(void* const* d_in, const int* in_sizes, int n_in,
                              void* d_out, int out_size, void* d_ws, size_t ws_size,
                              hipStream_t stream) {
  const float* x   = (const float*)d_in[0];
  const float* ctx = (const float*)d_in[1];
  const float* Wq  = (const float*)d_in[2];
  const float* Wk  = (const float*)d_in[3];
  const float* Wv  = (const float*)d_in[4];
  const float* Wo  = (const float*)d_in[5];
  const float* bo  = (const float*)d_in[6];
  float* out = (float*)d_out;

  char* ws = (char*)d_ws;
  u16* xb  = (u16*)(ws);                    // x bf16        [16384][1024] 32MB
  u16* cb  = (u16*)(ws + 33554432);         // context bf16  [4096][768]    6MB
  u16* wqt = (u16*)(ws + 39845888);         // WqT [1024][1024]             2MB
  u16* wkt = (u16*)(ws + 41943040);         // WkT [1024][768]            1.5MB
  u16* wvt = (u16*)(ws + 43515904);         // WvT [1024][768]            1.5MB
  u16* wot = (u16*)(ws + 45088768);         // WoT [1024][1024]             2MB
  u16* Qb  = (u16*)(ws + 47185920);         // Q bf16 [16384][1024]        32MB
  u16* Kb  = (u16*)(ws + 80740352);         // K bf16 [4096][1024]          8MB
  u16* VTb = (u16*)(ws + 89128960);         // V^T bf16 [1024][4096]        8MB
  u16* AOb = xb;                            // reuse: xb dead after Q-proj

  prep_kernel<<<23552, 256, 0, stream>>>(x, xb, 4194304, ctx, cb, 786432,
                                         Wq, Wk, Wv, Wo, wqt, wkt, wvt, wot);

  // Q pre-scaled by dim_head^-0.5 * log2(e) so attention softmax uses exp2
  const float qscale = 0.125f * 1.44269504088896f;
  proj3<<<1536, 256, 0, stream>>>(xb, wqt, Qb, qscale, cb, wkt, Kb, wvt, VTb);

  // fused attention (4 waves x 64 q-rows = 256 q-rows per block)
  attn_kernel<<<dim3(16, 64), 256, 0, stream>>>(Qb, Kb, VTb, AOb);

  // output projection (f32 out + bias)
  gemm_bt<1><<<dim3(8, 128), 256, 0, stream>>>(AOb, wot, nullptr, out, bo, 1.0f, 1024, 1024);
}

// Round 14
// 210.877 us; speedup vs baseline: 2.1912x; 2.1912x over previous
//
#include <hip/hip_runtime.h>
#include <hip/hip_bf16.h>

typedef unsigned short u16;
typedef __attribute__((ext_vector_type(8))) short short8;
typedef __attribute__((ext_vector_type(4))) float f32x4;
typedef __attribute__((ext_vector_type(16))) float f32x16;
typedef __attribute__((ext_vector_type(2))) unsigned uint2v;

#define ATT_B 4
#define ATT_N 4096
#define ATT_M 1024
#define ATT_H 16
#define CBLK 64
#define NT (ATT_M / CBLK)

__device__ inline u16 f2bf(float f) {
  union { float f; unsigned u; } x; x.f = f;
  unsigned r = x.u + 0x7fffu + ((x.u >> 16) & 1u);
  return (u16)(r >> 16);
}

// packed f32x2 -> bf16x2 (RNE), low word = lo
__device__ inline unsigned pk_bf16(float lo, float hi) {
  unsigned r;
  asm("v_cvt_pk_bf16_f32 %0, %1, %2" : "=v"(r) : "v"(lo), "v"(hi));
  return r;
}

// raw v_exp_f32 (2^x), no libm range fixup — inputs here are bounded |x|<~40
__device__ inline float exp2_raw(float x) {
  float r;
  asm("v_exp_f32 %0, %1" : "=v"(r) : "v"(x));
  return r;
}

__device__ inline void gload_lds16(const u16* g, u16* l) {
  __builtin_amdgcn_global_load_lds(
      (const __attribute__((address_space(1))) void*)g,
      (__attribute__((address_space(3))) void*)l, 16, 0, 0);
}

// ------- prep: weight transpose-casts + x/ctx casts in ONE launch ----------
__global__ __launch_bounds__(256) void prep_kernel(
    const float* __restrict__ x, u16* __restrict__ xb, int n4x,
    const float* __restrict__ ctx, u16* __restrict__ cb, int n4c,
    const float* __restrict__ Wq, const float* __restrict__ Wk,
    const float* __restrict__ Wv, const float* __restrict__ Wo,
    u16* __restrict__ wqt, u16* __restrict__ wkt,
    u16* __restrict__ wvt, u16* __restrict__ wot) {
  const int blk = blockIdx.x;
  const int tid = threadIdx.x;
  if (blk < 4096) {
    const int z = blk >> 10;
    const float* W = (z == 0) ? Wq : (z == 1) ? Wk : (z == 2) ? Wv : Wo;
    u16* Wt = (z == 0) ? wqt : (z == 1) ? wkt : (z == 2) ? wvt : wot;
    const int K = (z == 0 || z == 3) ? 1024 : 768;
    const int k0 = ((blk >> 5) & 31) * 32;
    if (k0 >= K) return;
    const int n0 = (blk & 31) * 32;
    __shared__ float T[32][33];
    const int tx = tid & 31, ty = tid >> 5;   // (32, 8)
#pragma unroll
    for (int i = 0; i < 4; ++i)
      T[ty + i * 8][tx] = W[(size_t)(k0 + ty + i * 8) * 1024 + n0 + tx];
    __syncthreads();
#pragma unroll
    for (int i = 0; i < 4; ++i)
      Wt[(size_t)(n0 + ty + i * 8) * K + k0 + tx] = f2bf(T[tx][ty + i * 8]);
  } else {
    int i = (blk - 4096) * 256 + tid;
    const float* src;
    u16* dst;
    if (i < n4x) {
      src = x; dst = xb;
    } else {
      i -= n4x;
      if (i >= n4c) return;
      src = ctx; dst = cb;
    }
    const float4 v = reinterpret_cast<const float4*>(src)[i];
    uint2 o;
    o.x = pk_bf16(v.x, v.y);
    o.y = pk_bf16(v.z, v.w);
    reinterpret_cast<uint2*>(dst)[i] = o;
  }
}

// -------- gemm body: BK=64, row-major LDS + XOR swizzle, XCD swizzle -------
// 128x128 tile, 4 waves (2x2), 32 MFMA per barrier-pair. LDS [128][64 bf16]
// with chunk swizzle (chunk q of row r at LDS chunk q^(r&7)), realized via
// pre-permuted gload source + swizzled ds_read (rule #21: both sides).
template <int F32OUT>
__device__ __forceinline__ void gemm_body(const u16* __restrict__ A,
                                          const u16* __restrict__ Bt,
                                          u16* __restrict__ Cb,
                                          float* __restrict__ Cf,
                                          const float* __restrict__ bias,
                                          float scale, int N, int K,
                                          unsigned orig, unsigned gx, unsigned nwg,
                                          u16* As, u16* Bs) {
  const int tid = threadIdx.x;
  const int lane = tid & 63;
  const int w = tid >> 6;
  const int lr = lane & 15;
  const int lk = lane >> 4;
  const int wm = w >> 1, wn = w & 1;

  // XCD-aware swizzle (segment sizes always % 8 == 0)
  const unsigned cpx = nwg >> 3;
  const unsigned swz = (orig & 7u) * cpx + (orig >> 3);
  const int brow = (int)(swz / gx) * 128;
  const int bcol = (int)(swz % gx) * 128;

  const int gr = lane >> 3;              // row within 8-row group
  const int gc = (lane & 7) ^ gr;        // permuted 16B chunk (0..7)

  f32x4 acc[4][4];
#pragma unroll
  for (int mi = 0; mi < 4; ++mi)
#pragma unroll
    for (int ni = 0; ni < 4; ++ni) acc[mi][ni] = f32x4{0.f, 0.f, 0.f, 0.f};

  for (int k0 = 0; k0 < K; k0 += 64) {
#pragma unroll
    for (int i = 0; i < 4; ++i) {
      const int g = w * 4 + i;           // 8-row group 0..15, wave-uniform
      gload_lds16(A + (size_t)(brow + g * 8 + gr) * K + k0 + gc * 8, &As[g * 512]);
      gload_lds16(Bt + (size_t)(bcol + g * 8 + gr) * K + k0 + gc * 8, &Bs[g * 512]);
    }
    __syncthreads();
    short8 a[4][2], bb[4][2];
#pragma unroll
    for (int mi = 0; mi < 4; ++mi) {
      const int row = wm * 64 + mi * 16 + lr;
#pragma unroll
      for (int kk = 0; kk < 2; ++kk)
        a[mi][kk] = *reinterpret_cast<const short8*>(
            &As[row * 64 + (((kk * 4 + lk) ^ (lr & 7)) * 8)]);
    }
#pragma unroll
    for (int ni = 0; ni < 4; ++ni) {
      const int row = wn * 64 + ni * 16 + lr;
#pragma unroll
      for (int kk = 0; kk < 2; ++kk)
        bb[ni][kk] = *reinterpret_cast<const short8*>(
            &Bs[row * 64 + (((kk * 4 + lk) ^ (lr & 7)) * 8)]);
    }
#pragma unroll
    for (int mi = 0; mi < 4; ++mi)
#pragma unroll
      for (int ni = 0; ni < 4; ++ni)
#pragma unroll
        for (int kk = 0; kk < 2; ++kk)
          acc[mi][ni] = __builtin_amdgcn_mfma_f32_16x16x32_bf16(
              a[mi][kk], bb[ni][kk], acc[mi][ni], 0, 0, 0);
    __syncthreads();
  }

#pragma unroll
  for (int mi = 0; mi < 4; ++mi)
#pragma unroll
    for (int ni = 0; ni < 4; ++ni)
#pragma unroll
      for (int r = 0; r < 4; ++r) {
        const size_t row = (size_t)(brow + wm * 64 + mi * 16 + lk * 4 + r);
        const int col = bcol + wn * 64 + ni * 16 + lr;
        if (F32OUT)
          Cf[row * N + col] = acc[mi][ni][r] + bias[col];
        else
          Cb[row * N + col] = f2bf(acc[mi][ni][r] * scale);
      }
}

// ---- proj3: Q-proj ∥ K-proj ∥ V^T-proj in one dispatch (segment decode) ---
// blocks [0,1024): Q = xb @ WqT^T  (16384x1024, K=1024, gx=8)
// blocks [1024,1280): K = cb @ WkT^T (4096x1024, K=768, gx=8)
// blocks [1280,1536): V^T = wvt @ cb^T (1024x4096, K=768, gx=32)
__global__ __launch_bounds__(256) void proj3(
    const u16* __restrict__ xb, const u16* __restrict__ wqt, u16* __restrict__ Qb,
    float qscale,
    const u16* __restrict__ cb, const u16* __restrict__ wkt, u16* __restrict__ Kb,
    const u16* __restrict__ wvt, u16* __restrict__ VTb) {
  __shared__ u16 As[128 * 64];
  __shared__ u16 Bs[128 * 64];
  const unsigned blk = blockIdx.x;
  if (blk < 1024)
    gemm_body<0>(xb, wqt, Qb, nullptr, nullptr, qscale, 1024, 1024,
                 blk, 8u, 1024u, As, Bs);
  else if (blk < 1280)
    gemm_body<0>(cb, wkt, Kb, nullptr, nullptr, 1.0f, 1024, 768,
                 blk - 1024u, 8u, 256u, As, Bs);
  else
    gemm_body<0>(wvt, cb, VTb, nullptr, nullptr, 1.0f, 4096, 768,
                 blk - 1280u, 32u, 256u, As, Bs);
}

// ---- out-projection (f32 out + bias) --------------------------------------
template <int F32OUT>
__global__ __launch_bounds__(256) void gemm_bt(const u16* __restrict__ A,
                                               const u16* __restrict__ Bt,
                                               u16* __restrict__ Cb,
                                               float* __restrict__ Cf,
                                               const float* __restrict__ bias,
                                               float scale, int N, int K) {
  __shared__ u16 As[128 * 64];
  __shared__ u16 Bs[128 * 64];
  const unsigned gx = gridDim.x;
  const unsigned nwg = gx * gridDim.y;
  const unsigned orig = blockIdx.y * gx + blockIdx.x;
  gemm_body<F32OUT>(A, Bt, Cb, Cf, bias, scale, N, K, orig, gx, nwg, As, Bs);
}

// ---------------- flash attention v7: 8 warps / 256 q-rows per block -------
// grid: (N/256, B*H), 512 threads = 8 warps x 32 q-rows. CBLK=64.
// S^T = mfma_32x32x16(K-frag, Q-frag); P = exp2 lane-local (raw v_exp_f32);
// PV A-frags via cvt_pk + permlane32_swap; row-sum via ones-MFMA.
// No max subtraction (scores bounded; shift cancels in the divide).
// NOTE (round 13 lesson): the 64-q/wave variant spills (needs >168 VGPR at
// 3 waves/SIMD; VGPR_Count=84 + 1GB scratch traffic was the signature).
// This 32-q/wave form is 60 VGPR, zero spill — keep it.
__global__ __launch_bounds__(512, 4) void attn_kernel(const u16* __restrict__ Qg,
                                                      const u16* __restrict__ Kg,
                                                      const u16* __restrict__ VTg,
                                                      u16* __restrict__ AO) {
  __shared__ u16 Ks[2][8][512];   // K frag f=ci*4+kc: K[ct+ci*32+l][kc*16+hi*8+j]
  __shared__ u16 Vs[2][8][512];   // V frag f=dj*4+kc: V[ct+kc*16+hi*8+j][dj*32+l]

  const int tid = threadIdx.x;
  const int lane = tid & 63;
  const int w = tid >> 6;          // 0..7
  const int l = lane & 31;
  const int hi = lane >> 5;
  const int qt = blockIdx.x;
  const int bh = blockIdx.y;
  const int b = bh >> 4, h = bh & 15;
  const int qbase = qt * 256 + w * 32;

  short8 qf[4];
#pragma unroll
  for (int kc = 0; kc < 4; ++kc)
    qf[kc] = *reinterpret_cast<const short8*>(
        Qg + (size_t)(b * ATT_N + qbase + l) * 1024 + h * 64 + kc * 16 + hi * 8);

  // wave w stages K-frag w and V-frag w
  const u16* ksrc = Kg + (size_t)(b * ATT_M + (w >> 2) * 32 + l) * 1024 + h * 64 + (w & 3) * 16 + hi * 8;
  const u16* vsrc = VTg + (size_t)(h * 64 + (w >> 2) * 32 + l) * (ATT_B * ATT_M) + b * ATT_M + (w & 3) * 16 + hi * 8;

  f32x16 Oacc[2], lsums;
#pragma unroll
  for (int r = 0; r < 16; ++r) { Oacc[0][r] = 0.f; Oacc[1][r] = 0.f; lsums[r] = 0.f; }

  union { unsigned u[4]; short8 s; } onesu;
  onesu.u[0] = onesu.u[1] = onesu.u[2] = onesu.u[3] = 0x3F803F80u;
  const short8 ones = onesu.s;

  gload_lds16(ksrc, &Ks[0][w][0]);
  gload_lds16(vsrc, &Vs[0][w][0]);
  __syncthreads();

  int buf = 0;
  for (int t = 0; t < NT; ++t) {
    if (t + 1 < NT) {
      gload_lds16(ksrc + (size_t)(t + 1) * CBLK * 1024, &Ks[buf ^ 1][w][0]);
      gload_lds16(vsrc + (size_t)(t + 1) * CBLK, &Vs[buf ^ 1][w][0]);
    }

    f32x16 st[2];
#pragma unroll
    for (int r = 0; r < 16; ++r) { st[0][r] = 0.f; st[1][r] = 0.f; }
    __builtin_amdgcn_s_setprio(1);
#pragma unroll
    for (int ci = 0; ci < 2; ++ci)
#pragma unroll
      for (int kc = 0; kc < 4; ++kc) {
        short8 kb = *reinterpret_cast<const short8*>(&Ks[buf][ci * 4 + kc][lane * 8]);
        st[ci] = __builtin_amdgcn_mfma_f32_32x32x16_bf16(kb, qf[kc], st[ci], 0, 0, 0);
      }
    __builtin_amdgcn_s_setprio(0);

    short8 pa[4];
#pragma unroll
    for (int ci = 0; ci < 2; ++ci) {
      float p[16];
#pragma unroll
      for (int r = 0; r < 16; ++r) p[r] = exp2_raw(st[ci][r]);
      unsigned Y0 = pk_bf16(p[0], p[1]),   Y1 = pk_bf16(p[2], p[3]);
      unsigned Y2 = pk_bf16(p[4], p[5]),   Y3 = pk_bf16(p[6], p[7]);
      unsigned Y4 = pk_bf16(p[8], p[9]),   Y5 = pk_bf16(p[10], p[11]);
      unsigned Y6 = pk_bf16(p[12], p[13]), Y7 = pk_bf16(p[14], p[15]);
      uint2v s02 = __builtin_amdgcn_permlane32_swap(Y0, Y2, false, false);
      uint2v s13 = __builtin_amdgcn_permlane32_swap(Y1, Y3, false, false);
      uint2v s46 = __builtin_amdgcn_permlane32_swap(Y4, Y6, false, false);
      uint2v s57 = __builtin_amdgcn_permlane32_swap(Y5, Y7, false, false);
      union { unsigned u[4]; short8 s; } f0, f1;
      f0.u[0] = s02.x; f0.u[1] = s13.x; f0.u[2] = s02.y; f0.u[3] = s13.y;
      f1.u[0] = s46.x; f1.u[1] = s57.x; f1.u[2] = s46.y; f1.u[3] = s57.y;
      pa[ci * 2 + 0] = f0.s;
      pa[ci * 2 + 1] = f1.s;
    }

    __builtin_amdgcn_s_setprio(1);
#pragma unroll
    for (int kcc = 0; kcc < 4; ++kcc) {
#pragma unroll
      for (int dj = 0; dj < 2; ++dj) {
        short8 vb = *reinterpret_cast<const short8*>(&Vs[buf][dj * 4 + kcc][lane * 8]);
        Oacc[dj] = __builtin_amdgcn_mfma_f32_32x32x16_bf16(pa[kcc], vb, Oacc[dj], 0, 0, 0);
      }
      lsums = __builtin_amdgcn_mfma_f32_32x32x16_bf16(pa[kcc], ones, lsums, 0, 0, 0);
    }
    __builtin_amdgcn_s_setprio(0);

    __syncthreads();
    buf ^= 1;
  }

#pragma unroll
  for (int r = 0; r < 16; ++r) {
    const float inv = __builtin_amdgcn_rcpf(lsums[r]);
    const int crow = (r & 3) + 8 * (r >> 2) + 4 * hi;
    const size_t row = (size_t)(b * ATT_N + qbase + crow);
#pragma unroll
    for (int dj = 0; dj < 2; ++dj)
      AO[row * 1024 + h * 64 + dj * 32 + l] = f2bf(Oacc[dj][r] * inv);
  }
}

// ---------------------------------------------------------------------------
extern "C" void kernel_launch(void* const* d_in, const int* in_sizes, int n_in,
                              void* d_out, int out_size, void* d_ws, size_t ws_size,
                              hipStream_t stream) {
  const float* x   = (const float*)d_in[0];
  const float* ctx = (const float*)d_in[1];
  const float* Wq  = (const float*)d_in[2];
  const float* Wk  = (const float*)d_in[3];
  const float* Wv  = (const float*)d_in[4];
  const float* Wo  = (const float*)d_in[5];
  const float* bo  = (const float*)d_in[6];
  float* out = (float*)d_out;

  char* ws = (char*)d_ws;
  u16* xb  = (u16*)(ws);                    // x bf16        [16384][1024] 32MB
  u16* cb  = (u16*)(ws + 33554432);         // context bf16  [4096][768]    6MB
  u16* wqt = (u16*)(ws + 39845888);         // WqT [1024][1024]             2MB
  u16* wkt = (u16*)(ws + 41943040);         // WkT [1024][768]            1.5MB
  u16* wvt = (u16*)(ws + 43515904);         // WvT [1024][768]            1.5MB
  u16* wot = (u16*)(ws + 45088768);         // WoT [1024][1024]             2MB
  u16* Qb  = (u16*)(ws + 47185920);         // Q bf16 [16384][1024]        32MB
  u16* Kb  = (u16*)(ws + 80740352);         // K bf16 [4096][1024]          8MB
  u16* VTb = (u16*)(ws + 89128960);         // V^T bf16 [1024][4096]        8MB
  u16* AOb = xb;                            // reuse: xb dead after Q-proj

  prep_kernel<<<23552, 256, 0, stream>>>(x, xb, 4194304, ctx, cb, 786432,
                                         Wq, Wk, Wv, Wo, wqt, wkt, wvt, wot);

  // Q pre-scaled by dim_head^-0.5 * log2(e) so attention softmax uses exp2
  const float qscale = 0.125f * 1.44269504088896f;
  proj3<<<1536, 256, 0, stream>>>(xb, wqt, Qb, qscale, cb, wkt, Kb, wvt, VTb);

  // fused attention (8-warp blocks, 256 q-rows each)
  attn_kernel<<<dim3(16, 64), 512, 0, stream>>>(Qb, Kb, VTb, AOb);

  // output projection (f32 out + bias)
  gemm_bt<1><<<dim3(8, 128), 256, 0, stream>>>(AOb, wot, nullptr, out, bo, 1.0f, 1024, 1024);
}

// Round 15
// 209.954 us; speedup vs baseline: 2.2008x; 1.0044x over previous
//
#include <hip/hip_runtime.h>
#include <hip/hip_bf16.h>

typedef unsigned short u16;
typedef __attribute__((ext_vector_type(8))) short short8;
typedef __attribute__((ext_vector_type(4))) float f32x4;
typedef __attribute__((ext_vector_type(16))) float f32x16;
typedef __attribute__((ext_vector_type(2))) unsigned uint2v;

#define ATT_B 4
#define ATT_N 4096
#define ATT_M 1024
#define ATT_H 16
#define CBLK 64
#define NT (ATT_M / CBLK)

__device__ inline u16 f2bf(float f) {
  union { float f; unsigned u; } x; x.f = f;
  unsigned r = x.u + 0x7fffu + ((x.u >> 16) & 1u);
  return (u16)(r >> 16);
}

// packed f32x2 -> bf16x2 (RNE), low word = lo
__device__ inline unsigned pk_bf16(float lo, float hi) {
  unsigned r;
  asm("v_cvt_pk_bf16_f32 %0, %1, %2" : "=v"(r) : "v"(lo), "v"(hi));
  return r;
}

// raw v_exp_f32 (2^x), no libm range fixup — inputs here are bounded |x|<~40
__device__ inline float exp2_raw(float x) {
  float r;
  asm("v_exp_f32 %0, %1" : "=v"(r) : "v"(x));
  return r;
}

__device__ inline void gload_lds16(const u16* g, u16* l) {
  __builtin_amdgcn_global_load_lds(
      (const __attribute__((address_space(1))) void*)g,
      (__attribute__((address_space(3))) void*)l, 16, 0, 0);
}

// ------- prep: weight transpose-casts + x/ctx casts in ONE launch ----------
__global__ __launch_bounds__(256) void prep_kernel(
    const float* __restrict__ x, u16* __restrict__ xb, int n4x,
    const float* __restrict__ ctx, u16* __restrict__ cb, int n4c,
    const float* __restrict__ Wq, const float* __restrict__ Wk,
    const float* __restrict__ Wv, const float* __restrict__ Wo,
    u16* __restrict__ wqt, u16* __restrict__ wkt,
    u16* __restrict__ wvt, u16* __restrict__ wot) {
  const int blk = blockIdx.x;
  const int tid = threadIdx.x;
  if (blk < 4096) {
    const int z = blk >> 10;
    const float* W = (z == 0) ? Wq : (z == 1) ? Wk : (z == 2) ? Wv : Wo;
    u16* Wt = (z == 0) ? wqt : (z == 1) ? wkt : (z == 2) ? wvt : wot;
    const int K = (z == 0 || z == 3) ? 1024 : 768;
    const int k0 = ((blk >> 5) & 31) * 32;
    if (k0 >= K) return;
    const int n0 = (blk & 31) * 32;
    __shared__ float T[32][33];
    const int tx = tid & 31, ty = tid >> 5;   // (32, 8)
#pragma unroll
    for (int i = 0; i < 4; ++i)
      T[ty + i * 8][tx] = W[(size_t)(k0 + ty + i * 8) * 1024 + n0 + tx];
    __syncthreads();
#pragma unroll
    for (int i = 0; i < 4; ++i)
      Wt[(size_t)(n0 + ty + i * 8) * K + k0 + tx] = f2bf(T[tx][ty + i * 8]);
  } else {
    int i = (blk - 4096) * 256 + tid;
    const float* src;
    u16* dst;
    if (i < n4x) {
      src = x; dst = xb;
    } else {
      i -= n4x;
      if (i >= n4c) return;
      src = ctx; dst = cb;
    }
    const float4 v = reinterpret_cast<const float4*>(src)[i];
    uint2 o;
    o.x = pk_bf16(v.x, v.y);
    o.y = pk_bf16(v.z, v.w);
    reinterpret_cast<uint2*>(dst)[i] = o;
  }
}

// -------- gemm body: BK=64, row-major LDS + XOR swizzle, XCD swizzle -------
// 128x128 tile, 4 waves (2x2), 32 MFMA per barrier-pair. LDS [128][64 bf16]
// with chunk swizzle (chunk q of row r at LDS chunk q^(r&7)), realized via
// pre-permuted gload source + swizzled ds_read (rule #21: both sides).
template <int F32OUT>
__device__ __forceinline__ void gemm_body(const u16* __restrict__ A,
                                          const u16* __restrict__ Bt,
                                          u16* __restrict__ Cb,
                                          float* __restrict__ Cf,
                                          const float* __restrict__ bias,
                                          float scale, int N, int K,
                                          unsigned orig, unsigned gx, unsigned nwg,
                                          u16* As, u16* Bs) {
  const int tid = threadIdx.x;
  const int lane = tid & 63;
  const int w = tid >> 6;
  const int lr = lane & 15;
  const int lk = lane >> 4;
  const int wm = w >> 1, wn = w & 1;

  // XCD-aware swizzle (segment sizes always % 8 == 0)
  const unsigned cpx = nwg >> 3;
  const unsigned swz = (orig & 7u) * cpx + (orig >> 3);
  const int brow = (int)(swz / gx) * 128;
  const int bcol = (int)(swz % gx) * 128;

  const int gr = lane >> 3;              // row within 8-row group
  const int gc = (lane & 7) ^ gr;        // permuted 16B chunk (0..7)

  f32x4 acc[4][4];
#pragma unroll
  for (int mi = 0; mi < 4; ++mi)
#pragma unroll
    for (int ni = 0; ni < 4; ++ni) acc[mi][ni] = f32x4{0.f, 0.f, 0.f, 0.f};

  for (int k0 = 0; k0 < K; k0 += 64) {
#pragma unroll
    for (int i = 0; i < 4; ++i) {
      const int g = w * 4 + i;           // 8-row group 0..15, wave-uniform
      gload_lds16(A + (size_t)(brow + g * 8 + gr) * K + k0 + gc * 8, &As[g * 512]);
      gload_lds16(Bt + (size_t)(bcol + g * 8 + gr) * K + k0 + gc * 8, &Bs[g * 512]);
    }
    __syncthreads();
    short8 a[4][2], bb[4][2];
#pragma unroll
    for (int mi = 0; mi < 4; ++mi) {
      const int row = wm * 64 + mi * 16 + lr;
#pragma unroll
      for (int kk = 0; kk < 2; ++kk)
        a[mi][kk] = *reinterpret_cast<const short8*>(
            &As[row * 64 + (((kk * 4 + lk) ^ (lr & 7)) * 8)]);
    }
#pragma unroll
    for (int ni = 0; ni < 4; ++ni) {
      const int row = wn * 64 + ni * 16 + lr;
#pragma unroll
      for (int kk = 0; kk < 2; ++kk)
        bb[ni][kk] = *reinterpret_cast<const short8*>(
            &Bs[row * 64 + (((kk * 4 + lk) ^ (lr & 7)) * 8)]);
    }
#pragma unroll
    for (int mi = 0; mi < 4; ++mi)
#pragma unroll
      for (int ni = 0; ni < 4; ++ni)
#pragma unroll
        for (int kk = 0; kk < 2; ++kk)
          acc[mi][ni] = __builtin_amdgcn_mfma_f32_16x16x32_bf16(
              a[mi][kk], bb[ni][kk], acc[mi][ni], 0, 0, 0);
    __syncthreads();
  }

#pragma unroll
  for (int mi = 0; mi < 4; ++mi)
#pragma unroll
    for (int ni = 0; ni < 4; ++ni)
#pragma unroll
      for (int r = 0; r < 4; ++r) {
        const size_t row = (size_t)(brow + wm * 64 + mi * 16 + lk * 4 + r);
        const int col = bcol + wn * 64 + ni * 16 + lr;
        if (F32OUT)
          Cf[row * N + col] = acc[mi][ni][r] + bias[col];
        else
          Cb[row * N + col] = f2bf(acc[mi][ni][r] * scale);
      }
}

// ---- proj3: Q-proj ∥ K-proj ∥ V^T-proj in one dispatch (segment decode) ---
__global__ __launch_bounds__(256) void proj3(
    const u16* __restrict__ xb, const u16* __restrict__ wqt, u16* __restrict__ Qb,
    float qscale,
    const u16* __restrict__ cb, const u16* __restrict__ wkt, u16* __restrict__ Kb,
    const u16* __restrict__ wvt, u16* __restrict__ VTb) {
  __shared__ u16 As[128 * 64];
  __shared__ u16 Bs[128 * 64];
  const unsigned blk = blockIdx.x;
  if (blk < 1024)
    gemm_body<0>(xb, wqt, Qb, nullptr, nullptr, qscale, 1024, 1024,
                 blk, 8u, 1024u, As, Bs);
  else if (blk < 1280)
    gemm_body<0>(cb, wkt, Kb, nullptr, nullptr, 1.0f, 1024, 768,
                 blk - 1024u, 8u, 256u, As, Bs);
  else
    gemm_body<0>(wvt, cb, VTb, nullptr, nullptr, 1.0f, 4096, 768,
                 blk - 1280u, 32u, 256u, As, Bs);
}

// ---- out-projection (f32 out + bias) --------------------------------------
template <int F32OUT>
__global__ __launch_bounds__(256) void gemm_bt(const u16* __restrict__ A,
                                               const u16* __restrict__ Bt,
                                               u16* __restrict__ Cb,
                                               float* __restrict__ Cf,
                                               const float* __restrict__ bias,
                                               float scale, int N, int K) {
  __shared__ u16 As[128 * 64];
  __shared__ u16 Bs[128 * 64];
  const unsigned gx = gridDim.x;
  const unsigned nwg = gx * gridDim.y;
  const unsigned orig = blockIdx.y * gx + blockIdx.x;
  gemm_body<F32OUT>(A, Bt, Cb, Cf, bias, scale, N, K, orig, gx, nwg, As, Bs);
}

// ------------- flash attention v7.5: scalar row-sum, no ones-MFMA ----------
// grid: (N/256, B*H), 512 threads = 8 warps x 32 q-rows. CBLK=64.
// S^T = mfma_32x32x16(K-frag, Q-frag): lane l holds the P-column for ONE
// q (=l), so the softmax denominator is a per-lane scalar sum folded into
// the exp2 loop (removes the 4 ones-MFMA per tile = 20% of matrix work,
// and 16 VGPRs of lsums). Epilogue: shfl_xor(32) + 1KB lsw redistribute
// (q=l -> crow(r,hi) layout). PV A-frags via cvt_pk + permlane32_swap.
// No max subtraction (scores bounded; shift cancels in the divide).
// NOTE (round 13 lesson): 64 q/wave spills (VGPR_Count=84 + scratch GBs);
// this 32-q form measured 60 VGPR, zero spill.
__global__ __launch_bounds__(512, 4) void attn_kernel(const u16* __restrict__ Qg,
                                                      const u16* __restrict__ Kg,
                                                      const u16* __restrict__ VTg,
                                                      u16* __restrict__ AO) {
  __shared__ u16 Ks[2][8][512];   // K frag f=ci*4+kc: K[ct+ci*32+l][kc*16+hi*8+j]
  __shared__ u16 Vs[2][8][512];   // V frag f=dj*4+kc: V[ct+kc*16+hi*8+j][dj*32+l]
  __shared__ float lsw[8][32];

  const int tid = threadIdx.x;
  const int lane = tid & 63;
  const int w = tid >> 6;          // 0..7
  const int l = lane & 31;
  const int hi = lane >> 5;
  const int qt = blockIdx.x;
  const int bh = blockIdx.y;
  const int b = bh >> 4, h = bh & 15;
  const int qbase = qt * 256 + w * 32;

  short8 qf[4];
#pragma unroll
  for (int kc = 0; kc < 4; ++kc)
    qf[kc] = *reinterpret_cast<const short8*>(
        Qg + (size_t)(b * ATT_N + qbase + l) * 1024 + h * 64 + kc * 16 + hi * 8);

  // wave w stages K-frag w and V-frag w
  const u16* ksrc = Kg + (size_t)(b * ATT_M + (w >> 2) * 32 + l) * 1024 + h * 64 + (w & 3) * 16 + hi * 8;
  const u16* vsrc = VTg + (size_t)(h * 64 + (w >> 2) * 32 + l) * (ATT_B * ATT_M) + b * ATT_M + (w & 3) * 16 + hi * 8;

  f32x16 Oacc[2];
  float lsum = 0.f;
#pragma unroll
  for (int r = 0; r < 16; ++r) { Oacc[0][r] = 0.f; Oacc[1][r] = 0.f; }

  gload_lds16(ksrc, &Ks[0][w][0]);
  gload_lds16(vsrc, &Vs[0][w][0]);
  __syncthreads();

  int buf = 0;
  for (int t = 0; t < NT; ++t) {
    if (t + 1 < NT) {
      gload_lds16(ksrc + (size_t)(t + 1) * CBLK * 1024, &Ks[buf ^ 1][w][0]);
      gload_lds16(vsrc + (size_t)(t + 1) * CBLK, &Vs[buf ^ 1][w][0]);
    }

    f32x16 st[2];
#pragma unroll
    for (int r = 0; r < 16; ++r) { st[0][r] = 0.f; st[1][r] = 0.f; }
    __builtin_amdgcn_s_setprio(1);
#pragma unroll
    for (int ci = 0; ci < 2; ++ci)
#pragma unroll
      for (int kc = 0; kc < 4; ++kc) {
        short8 kb = *reinterpret_cast<const short8*>(&Ks[buf][ci * 4 + kc][lane * 8]);
        st[ci] = __builtin_amdgcn_mfma_f32_32x32x16_bf16(kb, qf[kc], st[ci], 0, 0, 0);
      }
    __builtin_amdgcn_s_setprio(0);

    short8 pa[4];
#pragma unroll
    for (int ci = 0; ci < 2; ++ci) {
      float p[16];
      float s = 0.f;
#pragma unroll
      for (int r = 0; r < 16; ++r) { p[r] = exp2_raw(st[ci][r]); s += p[r]; }
      lsum += s;
      unsigned Y0 = pk_bf16(p[0], p[1]),   Y1 = pk_bf16(p[2], p[3]);
      unsigned Y2 = pk_bf16(p[4], p[5]),   Y3 = pk_bf16(p[6], p[7]);
      unsigned Y4 = pk_bf16(p[8], p[9]),   Y5 = pk_bf16(p[10], p[11]);
      unsigned Y6 = pk_bf16(p[12], p[13]), Y7 = pk_bf16(p[14], p[15]);
      uint2v s02 = __builtin_amdgcn_permlane32_swap(Y0, Y2, false, false);
      uint2v s13 = __builtin_amdgcn_permlane32_swap(Y1, Y3, false, false);
      uint2v s46 = __builtin_amdgcn_permlane32_swap(Y4, Y6, false, false);
      uint2v s57 = __builtin_amdgcn_permlane32_swap(Y5, Y7, false, false);
      union { unsigned u[4]; short8 s; } f0, f1;
      f0.u[0] = s02.x; f0.u[1] = s13.x; f0.u[2] = s02.y; f0.u[3] = s13.y;
      f1.u[0] = s46.x; f1.u[1] = s57.x; f1.u[2] = s46.y; f1.u[3] = s57.y;
      pa[ci * 2 + 0] = f0.s;
      pa[ci * 2 + 1] = f1.s;
    }

    __builtin_amdgcn_s_setprio(1);
#pragma unroll
    for (int kcc = 0; kcc < 4; ++kcc)
#pragma unroll
      for (int dj = 0; dj < 2; ++dj) {
        short8 vb = *reinterpret_cast<const short8*>(&Vs[buf][dj * 4 + kcc][lane * 8]);
        Oacc[dj] = __builtin_amdgcn_mfma_f32_32x32x16_bf16(pa[kcc], vb, Oacc[dj], 0, 0, 0);
      }
    __builtin_amdgcn_s_setprio(0);

    __syncthreads();
    buf ^= 1;
  }

  // ---- epilogue: reduce + redistribute row sums (q=l -> crow layout) ----
  lsum += __shfl_xor(lsum, 32);
  if (hi == 0) lsw[w][l] = lsum;
  __syncthreads();
#pragma unroll
  for (int r = 0; r < 16; ++r) {
    const int crow = (r & 3) + 8 * (r >> 2) + 4 * hi;
    const float inv = __builtin_amdgcn_rcpf(lsw[w][crow]);
    const size_t row = (size_t)(b * ATT_N + qbase + crow);
#pragma unroll
    for (int dj = 0; dj < 2; ++dj)
      AO[row * 1024 + h * 64 + dj * 32 + l] = f2bf(Oacc[dj][r] * inv);
  }
}

// ---------------------------------------------------------------------------
extern "C" void kernel_launch(void* const* d_in, const int* in_sizes, int n_in,
                              void* d_out, int out_size, void* d_ws, size_t ws_size,
                              hipStream_t stream) {
  const float* x   = (const float*)d_in[0];
  const float* ctx = (const float*)d_in[1];
  const float* Wq  = (const float*)d_in[2];
  const float* Wk  = (const float*)d_in[3];
  const float* Wv  = (const float*)d_in[4];
  const float* Wo  = (const float*)d_in[5];
  const float* bo  = (const float*)d_in[6];
  float* out = (float*)d_out;

  char* ws = (char*)d_ws;
  u16* xb  = (u16*)(ws);                    // x bf16        [16384][1024] 32MB
  u16* cb  = (u16*)(ws + 33554432);         // context bf16  [4096][768]    6MB
  u16* wqt = (u16*)(ws + 39845888);         // WqT [1024][1024]             2MB
  u16* wkt = (u16*)(ws + 41943040);         // WkT [1024][768]            1.5MB
  u16* wvt = (u16*)(ws + 43515904);         // WvT [1024][768]            1.5MB
  u16* wot = (u16*)(ws + 45088768);         // WoT [1024][1024]             2MB
  u16* Qb  = (u16*)(ws + 47185920);         // Q bf16 [16384][1024]        32MB
  u16* Kb  = (u16*)(ws + 80740352);         // K bf16 [4096][1024]          8MB
  u16* VTb = (u16*)(ws + 89128960);         // V^T bf16 [1024][4096]        8MB
  u16* AOb = xb;                            // reuse: xb dead after Q-proj

  prep_kernel<<<23552, 256, 0, stream>>>(x, xb, 4194304, ctx, cb, 786432,
                                         Wq, Wk, Wv, Wo, wqt, wkt, wvt, wot);

  // Q pre-scaled by dim_head^-0.5 * log2(e) so attention softmax uses exp2
  const float qscale = 0.125f * 1.44269504088896f;
  proj3<<<1536, 256, 0, stream>>>(xb, wqt, Qb, qscale, cb, wkt, Kb, wvt, VTb);

  // fused attention (8-warp blocks, 256 q-rows each)
  attn_kernel<<<dim3(16, 64), 512, 0, stream>>>(Qb, Kb, VTb, AOb);

  // output projection (f32 out + bias)
  gemm_bt<1><<<dim3(8, 128), 256, 0, stream>>>(AOb, wot, nullptr, out, bo, 1.0f, 1024, 1024);
}